// Round 1
// baseline (374.627 us; speedup 1.0000x reference)
//
#include <hip/hip_runtime.h>

// GatedQueryAttLayer on MI355X (gfx950)
// B=16, S=512, E=1024, H=16, DK=64
// Pipeline: conv(inp->bf16) ; transpose+cvt(Wq/Wk/Wv -> W^T bf16) ;
//           fused QKV bf16-MFMA GEMM ; per-head gating (vector fp32) ;
//           flash attention (bf16 MFMA, exp2 online softmax).
// Workspace: 70 MB.

typedef __bf16 bf16;
typedef __bf16 bf16x8 __attribute__((ext_vector_type(8)));
typedef __bf16 bf16x4 __attribute__((ext_vector_type(4)));
typedef float  f32x4  __attribute__((ext_vector_type(4)));

#define MFMA16(a,b,c) __builtin_amdgcn_mfma_f32_16x16x32_bf16((a),(b),(c),0,0,0)

// async global->LDS, 16B per lane; LDS dest is wave-uniform base + lane*16,
// so lds layout must be linear in lane order (it is, below).
#define GLL16(gp, lp)                                                          \
  __builtin_amdgcn_global_load_lds(                                            \
      (__attribute__((address_space(1))) void*)(void*)(gp),                    \
      (__attribute__((address_space(3))) void*)(lp), 16, 0, 0)

// ---------------------------------------------------------------- conv inp
__global__ __launch_bounds__(256) void k_conv_inp(const float* __restrict__ in,
                                                  bf16* __restrict__ out) {
  int i = blockIdx.x * 256 + threadIdx.x;   // 4 elems per thread
  float4 v = ((const float4*)in)[i];
  bf16x4 o;
  o[0] = (bf16)v.x; o[1] = (bf16)v.y; o[2] = (bf16)v.z; o[3] = (bf16)v.w;
  ((bf16x4*)out)[i] = o;
}

// ------------------------------------------- weight transpose + cvt to bf16
// W[k][n] fp32 (1024x1024) -> WT[n][k] bf16, for Wq/Wk/Wv (blockIdx.z)
__global__ __launch_bounds__(256) void k_wt(const float* __restrict__ Wq,
                                            const float* __restrict__ Wk,
                                            const float* __restrict__ Wv,
                                            bf16* __restrict__ WT) {
  __shared__ float tile[32][33];
  const int mat = blockIdx.z;
  const float* W = (mat == 0) ? Wq : ((mat == 1) ? Wk : Wv);
  bf16* O = WT + (size_t)mat * (1024 * 1024);
  const int kb = blockIdx.x, nb = blockIdx.y;
  const int t = threadIdx.x, tr = t >> 3, tc = (t & 7) * 4;
  float4 v = *(const float4*)&W[(size_t)(kb * 32 + tr) * 1024 + nb * 32 + tc];
  tile[tr][tc] = v.x; tile[tr][tc + 1] = v.y;
  tile[tr][tc + 2] = v.z; tile[tr][tc + 3] = v.w;
  __syncthreads();
  bf16x4 o;
  o[0] = (bf16)tile[tc][tr];     o[1] = (bf16)tile[tc + 1][tr];
  o[2] = (bf16)tile[tc + 2][tr]; o[3] = (bf16)tile[tc + 3][tr];
  *(bf16x4*)&O[(size_t)(nb * 32 + tr) * 1024 + kb * 32 + tc] = o;
}

// -------------------------------------------------- fused QKV projection GEMM
// X[8192][1024] bf16 @ W^T -> q/k: [B,S,H,DK] bf16 ; v: [B,H,DK,S] bf16 (V^T)
// m97 structure: BM=BN=128, BK=32, 256 thr (4 waves, 2x2 of 64x64), 16x16x32.
__global__ __launch_bounds__(256) void k_proj(const bf16* __restrict__ X,
                                              const bf16* __restrict__ WT,
                                              const float* __restrict__ bq,
                                              const float* __restrict__ bk,
                                              const float* __restrict__ bv,
                                              bf16* __restrict__ qw,
                                              bf16* __restrict__ kw,
                                              bf16* __restrict__ vt) {
  __shared__ bf16 As[128 * 32];
  __shared__ bf16 Bs[128 * 32];
  const int tid = threadIdx.x;
  const int m0 = blockIdx.x * 128;
  const int by = blockIdx.y;
  const int mat = by >> 3;             // 0=q,1=k,2=v
  const int n0 = (by & 7) * 128;       // within this matrix's 1024 cols
  const bf16* Wt = WT + (size_t)mat * (1024 * 1024);
  const float* bias = (mat == 0) ? bq : ((mat == 1) ? bk : bv);
  const int l = tid & 63, w = tid >> 6;
  const int wm = w >> 1, wn = w & 1;
  const int l4 = l & 15, q8 = l >> 4;

  f32x4 acc[4][4] = {};
  for (int kt = 0; kt < 1024; kt += 32) {
    __syncthreads();
#pragma unroll
    for (int i = 0; i < 2; ++i) {
      int chunk = i * 256 + tid;                       // 8 bf16 per chunk
      GLL16(X  + (size_t)(m0 + (chunk >> 2)) * 1024 + kt + (chunk & 3) * 8,
            As + chunk * 8);
      GLL16(Wt + (size_t)(n0 + (chunk >> 2)) * 1024 + kt + (chunk & 3) * 8,
            Bs + chunk * 8);
    }
    __syncthreads();
    bf16x8 a[4], b[4];
#pragma unroll
    for (int i = 0; i < 4; ++i)
      a[i] = *(const bf16x8*)&As[(wm * 64 + i * 16 + l4) * 32 + q8 * 8];
#pragma unroll
    for (int j = 0; j < 4; ++j)
      b[j] = *(const bf16x8*)&Bs[(wn * 64 + j * 16 + l4) * 32 + q8 * 8];
#pragma unroll
    for (int i = 0; i < 4; ++i)
#pragma unroll
      for (int j = 0; j < 4; ++j)
        acc[i][j] = MFMA16(a[i], b[j], acc[i][j]);
  }
  // epilogue: +bias, cvt bf16, scatter to layout
#pragma unroll
  for (int j = 0; j < 4; ++j) {
    int n = n0 + wn * 64 + j * 16 + l4;   // 0..1023 ; h = n>>6, d = n&63
    float bb = bias[n];
#pragma unroll
    for (int i = 0; i < 4; ++i) {
#pragma unroll
      for (int r = 0; r < 4; ++r) {
        int m = m0 + wm * 64 + i * 16 + q8 * 4 + r;  // 0..8191 = b*512+s
        bf16 val = (bf16)(acc[i][j][r] + bb);
        if (mat == 2) {
          int b_ = m >> 9, s = m & 511, h = n >> 6, d = n & 63;
          vt[((size_t)(b_ * 16 + h) * 64 + d) * 512 + s] = val;
        } else if (mat == 0) {
          qw[(size_t)m * 1024 + n] = val;   // [B,S,H,DK] flat
        } else {
          kw[(size_t)m * 1024 + n] = val;
        }
      }
    }
  }
}

// ----------------------------------------------------------------- gating
// thread-per-token(b,s,h): fq=q@Wfq+bfq ; fk=k@Wfk+bfk ; M=sigmoid((fq*fk)@Wfg+bfg)
// q'=q*M[:64]*(log2e/8) ; k'=k*M[64:]. Weights via uniform scalar loads;
// dynamic-indexed q/k/G live in a per-thread LDS column (conflict-free).
__global__ __launch_bounds__(256, 2) void k_gate(bf16* __restrict__ qw,
                                                 bf16* __restrict__ kw,
                                                 const float* __restrict__ Wfq,
                                                 const float* __restrict__ bfq,
                                                 const float* __restrict__ Wfk,
                                                 const float* __restrict__ bfk,
                                                 const float* __restrict__ Wfg,
                                                 const float* __restrict__ bfg) {
  __shared__ float Gs[64 * 256];   // 64KB: one 64-float column per thread
  const int tid = threadIdx.x;
  const size_t tok = (size_t)blockIdx.x * 256 + tid;   // (b,s,h) flat
  bf16* qp = qw + tok * 64;
  bf16* kp = kw + tok * 64;

  // ---- fq
#pragma unroll
  for (int jj = 0; jj < 8; ++jj) {
    bf16x8 v = *(const bf16x8*)&qp[jj * 8];
#pragma unroll
    for (int e = 0; e < 8; ++e) Gs[(jj * 8 + e) * 256 + tid] = (float)v[e];
  }
  float fq[64];
#pragma unroll
  for (int d = 0; d < 64; ++d) fq[d] = bfq[d];
#pragma unroll 4
  for (int j = 0; j < 64; ++j) {
    float qj = Gs[j * 256 + tid];
    const float* row = Wfq + j * 64;   // uniform -> s_load
#pragma unroll
    for (int d = 0; d < 64; ++d) fq[d] = fmaf(qj, row[d], fq[d]);
  }
  // ---- fk
#pragma unroll
  for (int jj = 0; jj < 8; ++jj) {
    bf16x8 v = *(const bf16x8*)&kp[jj * 8];
#pragma unroll
    for (int e = 0; e < 8; ++e) Gs[(jj * 8 + e) * 256 + tid] = (float)v[e];
  }
  float fk[64];
#pragma unroll
  for (int d = 0; d < 64; ++d) fk[d] = bfk[d];
#pragma unroll 4
  for (int j = 0; j < 64; ++j) {
    float kj = Gs[j * 256 + tid];
    const float* row = Wfk + j * 64;
#pragma unroll
    for (int d = 0; d < 64; ++d) fk[d] = fmaf(kj, row[d], fk[d]);
  }
  // ---- G -> LDS ; M = G @ Wfg + bfg
#pragma unroll
  for (int d = 0; d < 64; ++d) Gs[d * 256 + tid] = fq[d] * fk[d];
  float M[128];
#pragma unroll
  for (int dd = 0; dd < 128; ++dd) M[dd] = bfg[dd];
#pragma unroll 2
  for (int j = 0; j < 64; ++j) {
    float gj = Gs[j * 256 + tid];
    const float* row = Wfg + j * 128;
#pragma unroll
    for (int dd = 0; dd < 128; ++dd) M[dd] = fmaf(gj, row[dd], M[dd]);
  }
#pragma unroll
  for (int dd = 0; dd < 128; ++dd) M[dd] = 1.0f / (1.0f + __expf(-M[dd]));

  const float SC = 0.18033688011112042f;  // log2(e)/8 folded into Q
#pragma unroll
  for (int jj = 0; jj < 8; ++jj) {
    bf16x8 v = *(const bf16x8*)&qp[jj * 8];
    bf16x8 o;
#pragma unroll
    for (int e = 0; e < 8; ++e) o[e] = (bf16)((float)v[e] * M[jj * 8 + e] * SC);
    *(bf16x8*)&qp[jj * 8] = o;
  }
#pragma unroll
  for (int jj = 0; jj < 8; ++jj) {
    bf16x8 v = *(const bf16x8*)&kp[jj * 8];
    bf16x8 o;
#pragma unroll
    for (int e = 0; e < 8; ++e) o[e] = (bf16)((float)v[e] * M[64 + jj * 8 + e]);
    *(bf16x8*)&kp[jj * 8] = o;
  }
}

// ------------------------------------------------------------- attention
// block: 256 thr (4 waves), 128 q-rows of one (b,h); wave = 32 rows (2 m-frags).
// K/V streamed in 128-key tiles; online softmax in exp2 domain (scale in Q).
// LDS padded (+8) to break 128B-stride bank aliasing on b128 frag reads.
__global__ __launch_bounds__(256, 2) void k_attn(const bf16* __restrict__ qw,
                                                 const bf16* __restrict__ kw,
                                                 const bf16* __restrict__ vt,
                                                 float* __restrict__ out) {
  __shared__ bf16 Kt[128 * 72];       // [key][dk] padded
  __shared__ bf16 Vt[64 * 136];       // [dk][key] padded (V^T)
  __shared__ bf16 Pb[4][32 * 40];     // per-wave P chunk [32 rows][32 keys] padded
  const int tid = threadIdx.x, w = tid >> 6, l = tid & 63;
  const int l4 = l & 15, q8 = l >> 4;
  const int bx = blockIdx.x, qc = bx & 3, bh = bx >> 2;
  const int b_ = bh >> 4, h = bh & 15;
  bf16* Pw = &Pb[w][0];

  bf16x8 qf[2][2];
#pragma unroll
  for (int i = 0; i < 2; ++i)
#pragma unroll
    for (int kk = 0; kk < 2; ++kk) {
      int s = qc * 128 + w * 32 + i * 16 + l4;
      qf[i][kk] = *(const bf16x8*)
          &qw[(((size_t)b_ * 512 + s) * 16 + h) * 64 + kk * 32 + q8 * 8];
    }

  f32x4 o[2][4] = {};
  float mrun[2][4], lrun[2][4];
#pragma unroll
  for (int i = 0; i < 2; ++i)
#pragma unroll
    for (int r = 0; r < 4; ++r) { mrun[i][r] = -3.0e38f; lrun[i][r] = 0.0f; }

  for (int t = 0; t < 4; ++t) {
    __syncthreads();
#pragma unroll
    for (int i = 0; i < 4; ++i) {
      int chunk = i * 256 + tid;
      {  // K tile: straight copy, [key][dk]
        int key = chunk >> 3, c8 = chunk & 7;
        bf16x8 v = *(const bf16x8*)
            &kw[(((size_t)b_ * 512 + t * 128 + key) * 16 + h) * 64 + c8 * 8];
        *(bf16x8*)&Kt[key * 72 + c8 * 8] = v;
      }
      {  // V^T tile: straight copy from global V^T, [dk][key]
        int d = chunk >> 4, c16 = chunk & 15;
        bf16x8 v = *(const bf16x8*)
            &vt[((size_t)bh * 64 + d) * 512 + t * 128 + c16 * 8];
        *(bf16x8*)&Vt[d * 136 + c16 * 8] = v;
      }
    }
    __syncthreads();

    // scores: D[q (2x16)][key (8x16)]
    f32x4 sc[2][8];
    const f32x4 fz = {};
#pragma unroll
    for (int c = 0; c < 8; ++c) {
      bf16x8 kb0 = *(const bf16x8*)&Kt[(c * 16 + l4) * 72 + q8 * 8];
      sc[0][c] = MFMA16(qf[0][0], kb0, fz);
      sc[1][c] = MFMA16(qf[1][0], kb0, fz);
      bf16x8 kb1 = *(const bf16x8*)&Kt[(c * 16 + l4) * 72 + 32 + q8 * 8];
      sc[0][c] = MFMA16(qf[0][1], kb1, sc[0][c]);
      sc[1][c] = MFMA16(qf[1][1], kb1, sc[1][c]);
    }

    // online softmax (exp2 domain); row stats shared by 16-lane groups
#pragma unroll
    for (int i = 0; i < 2; ++i) {
      float al[4];
#pragma unroll
      for (int r = 0; r < 4; ++r) {
        float mx = sc[i][0][r];
#pragma unroll
        for (int c = 1; c < 8; ++c) mx = fmaxf(mx, sc[i][c][r]);
        mx = fmaxf(mx, __shfl_xor(mx, 1));
        mx = fmaxf(mx, __shfl_xor(mx, 2));
        mx = fmaxf(mx, __shfl_xor(mx, 4));
        mx = fmaxf(mx, __shfl_xor(mx, 8));
        float mn = fmaxf(mrun[i][r], mx);
        al[r] = exp2f(mrun[i][r] - mn);
        mrun[i][r] = mn;
        float sm = 0.0f;
#pragma unroll
        for (int c = 0; c < 8; ++c) {
          float p = exp2f(sc[i][c][r] - mn);
          sc[i][c][r] = p;
          sm += p;
        }
        sm += __shfl_xor(sm, 1); sm += __shfl_xor(sm, 2);
        sm += __shfl_xor(sm, 4); sm += __shfl_xor(sm, 8);
        lrun[i][r] = lrun[i][r] * al[r] + sm;
      }
#pragma unroll
      for (int f = 0; f < 4; ++f)
#pragma unroll
        for (int r = 0; r < 4; ++r) o[i][f][r] *= al[r];
    }

    // PV: C/D-layout P -> LDS (32-key chunks) -> A-layout frags -> MFMA
#pragma unroll
    for (int kk2 = 0; kk2 < 4; ++kk2) {
#pragma unroll
      for (int i = 0; i < 2; ++i)
#pragma unroll
        for (int cc = 0; cc < 2; ++cc) {
          int c = kk2 * 2 + cc;
#pragma unroll
          for (int r = 0; r < 4; ++r)
            Pw[(i * 16 + q8 * 4 + r) * 40 + cc * 16 + l4] = (bf16)sc[i][c][r];
        }
      bf16x8 pa0 = *(const bf16x8*)&Pw[(l4) * 40 + q8 * 8];
      bf16x8 pa1 = *(const bf16x8*)&Pw[(16 + l4) * 40 + q8 * 8];
#pragma unroll
      for (int f = 0; f < 4; ++f) {
        bf16x8 vb = *(const bf16x8*)&Vt[(f * 16 + l4) * 136 + kk2 * 32 + q8 * 8];
        o[0][f] = MFMA16(pa0, vb, o[0][f]);
        o[1][f] = MFMA16(pa1, vb, o[1][f]);
      }
    }
  }

  // epilogue: normalize, write [B,S,E] fp32
#pragma unroll
  for (int i = 0; i < 2; ++i)
#pragma unroll
    for (int r = 0; r < 4; ++r) {
      int srow = qc * 128 + w * 32 + i * 16 + q8 * 4 + r;
      float inv = 1.0f / lrun[i][r];
#pragma unroll
      for (int f = 0; f < 4; ++f)
        out[(((size_t)b_ * 512 + srow) * 16 + h) * 64 + f * 16 + l4] =
            o[i][f][r] * inv;
    }
}

// ---------------------------------------------------------------- launcher
extern "C" void kernel_launch(void* const* d_in, const int* in_sizes, int n_in,
                              void* d_out, int out_size, void* d_ws,
                              size_t ws_size, hipStream_t stream) {
  (void)in_sizes; (void)n_in; (void)out_size; (void)ws_size;
  const float* inp = (const float*)d_in[0];
  const float* Wq  = (const float*)d_in[1];
  const float* bq  = (const float*)d_in[2];
  const float* Wk  = (const float*)d_in[3];
  const float* bk  = (const float*)d_in[4];
  const float* Wv  = (const float*)d_in[5];
  const float* bv  = (const float*)d_in[6];
  const float* Wfq = (const float*)d_in[7];
  const float* bfq = (const float*)d_in[8];
  const float* Wfk = (const float*)d_in[9];
  const float* bfk = (const float*)d_in[10];
  const float* Wfg = (const float*)d_in[11];
  const float* bfg = (const float*)d_in[12];
  float* out = (float*)d_out;

  char* ws = (char*)d_ws;
  bf16* Xb = (bf16*)(ws);                                // 16 MB
  bf16* WT = (bf16*)(ws + 16777216);                     // 6 MB (3x W^T)
  bf16* qw = (bf16*)(ws + 16777216 + 6291456);           // 16 MB [B,S,H,DK]
  bf16* kw = qw + 8388608;                               // 16 MB
  bf16* vt = kw + 8388608;                               // 16 MB [B,H,DK,S]

  k_conv_inp<<<8192, 256, 0, stream>>>(inp, Xb);
  k_wt<<<dim3(32, 32, 3), 256, 0, stream>>>(Wq, Wk, Wv, WT);
  k_proj<<<dim3(64, 24), 256, 0, stream>>>(Xb, WT, bq, bk, bv, qw, kw, vt);
  k_gate<<<512, 256, 0, stream>>>(qw, kw, Wfq, bfq, Wfk, bfk, Wfg, bfg);
  k_attn<<<1024, 256, 0, stream>>>(qw, kw, vt, out);
}

// Round 2
// 274.565 us; speedup vs baseline: 1.3644x; 1.3644x over previous
//
#include <hip/hip_runtime.h>

// GatedQueryAttLayer on MI355X (gfx950)
// B=16, S=512, E=1024, H=16, DK=64
// Pipeline: conv(inp->bf16) ; transpose+cvt(Wq/Wk/Wv -> W^T bf16) ;
//           fused QKV bf16-MFMA GEMM ; MFMA gating ; flash attention.
// Workspace: 70 MB.

typedef __bf16 bf16;
typedef __bf16 bf16x8 __attribute__((ext_vector_type(8)));
typedef __bf16 bf16x4 __attribute__((ext_vector_type(4)));
typedef float  f32x4  __attribute__((ext_vector_type(4)));

#define MFMA16(a,b,c) __builtin_amdgcn_mfma_f32_16x16x32_bf16((a),(b),(c),0,0,0)

// async global->LDS, 16B per lane; LDS dest is wave-uniform base + lane*16,
// so lds layout must be linear in lane order (it is, below).
#define GLL16(gp, lp)                                                          \
  __builtin_amdgcn_global_load_lds(                                            \
      (__attribute__((address_space(1))) void*)(void*)(gp),                    \
      (__attribute__((address_space(3))) void*)(lp), 16, 0, 0)

// ---------------------------------------------------------------- conv inp
__global__ __launch_bounds__(256) void k_conv_inp(const float* __restrict__ in,
                                                  bf16* __restrict__ out) {
  int i = blockIdx.x * 256 + threadIdx.x;   // 4 elems per thread
  float4 v = ((const float4*)in)[i];
  bf16x4 o;
  o[0] = (bf16)v.x; o[1] = (bf16)v.y; o[2] = (bf16)v.z; o[3] = (bf16)v.w;
  ((bf16x4*)out)[i] = o;
}

// ------------------------------------------- weight transpose + cvt to bf16
// W[k][n] fp32 (1024x1024) -> WT[n][k] bf16, for Wq/Wk/Wv (blockIdx.z)
__global__ __launch_bounds__(256) void k_wt(const float* __restrict__ Wq,
                                            const float* __restrict__ Wk,
                                            const float* __restrict__ Wv,
                                            bf16* __restrict__ WT) {
  __shared__ float tile[32][33];
  const int mat = blockIdx.z;
  const float* W = (mat == 0) ? Wq : ((mat == 1) ? Wk : Wv);
  bf16* O = WT + (size_t)mat * (1024 * 1024);
  const int kb = blockIdx.x, nb = blockIdx.y;
  const int t = threadIdx.x, tr = t >> 3, tc = (t & 7) * 4;
  float4 v = *(const float4*)&W[(size_t)(kb * 32 + tr) * 1024 + nb * 32 + tc];
  tile[tr][tc] = v.x; tile[tr][tc + 1] = v.y;
  tile[tr][tc + 2] = v.z; tile[tr][tc + 3] = v.w;
  __syncthreads();
  bf16x4 o;
  o[0] = (bf16)tile[tc][tr];     o[1] = (bf16)tile[tc + 1][tr];
  o[2] = (bf16)tile[tc + 2][tr]; o[3] = (bf16)tile[tc + 3][tr];
  *(bf16x4*)&O[(size_t)(nb * 32 + tr) * 1024 + kb * 32 + tc] = o;
}

// -------------------------------------------------- fused QKV projection GEMM
// X[8192][1024] bf16 @ W^T -> q/k: [B,S,H,DK] bf16 ; v: [B,H,DK,S] bf16 (V^T)
// m97 structure: BM=BN=128, BK=32, 256 thr (4 waves, 2x2 of 64x64), 16x16x32.
__global__ __launch_bounds__(256) void k_proj(const bf16* __restrict__ X,
                                              const bf16* __restrict__ WT,
                                              const float* __restrict__ bq,
                                              const float* __restrict__ bk,
                                              const float* __restrict__ bv,
                                              bf16* __restrict__ qw,
                                              bf16* __restrict__ kw,
                                              bf16* __restrict__ vt) {
  __shared__ bf16 As[128 * 32];
  __shared__ bf16 Bs[128 * 32];
  const int tid = threadIdx.x;
  const int m0 = blockIdx.x * 128;
  const int by = blockIdx.y;
  const int mat = by >> 3;             // 0=q,1=k,2=v
  const int n0 = (by & 7) * 128;       // within this matrix's 1024 cols
  const bf16* Wt = WT + (size_t)mat * (1024 * 1024);
  const float* bias = (mat == 0) ? bq : ((mat == 1) ? bk : bv);
  const int l = tid & 63, w = tid >> 6;
  const int wm = w >> 1, wn = w & 1;
  const int l4 = l & 15, q8 = l >> 4;

  f32x4 acc[4][4] = {};
  for (int kt = 0; kt < 1024; kt += 32) {
    __syncthreads();
#pragma unroll
    for (int i = 0; i < 2; ++i) {
      int chunk = i * 256 + tid;                       // 8 bf16 per chunk
      GLL16(X  + (size_t)(m0 + (chunk >> 2)) * 1024 + kt + (chunk & 3) * 8,
            As + chunk * 8);
      GLL16(Wt + (size_t)(n0 + (chunk >> 2)) * 1024 + kt + (chunk & 3) * 8,
            Bs + chunk * 8);
    }
    __syncthreads();
    bf16x8 a[4], b[4];
#pragma unroll
    for (int i = 0; i < 4; ++i)
      a[i] = *(const bf16x8*)&As[(wm * 64 + i * 16 + l4) * 32 + q8 * 8];
#pragma unroll
    for (int j = 0; j < 4; ++j)
      b[j] = *(const bf16x8*)&Bs[(wn * 64 + j * 16 + l4) * 32 + q8 * 8];
#pragma unroll
    for (int i = 0; i < 4; ++i)
#pragma unroll
      for (int j = 0; j < 4; ++j)
        acc[i][j] = MFMA16(a[i], b[j], acc[i][j]);
  }
  // epilogue: +bias, cvt bf16, scatter to layout
#pragma unroll
  for (int j = 0; j < 4; ++j) {
    int n = n0 + wn * 64 + j * 16 + l4;   // 0..1023 ; h = n>>6, d = n&63
    float bb = bias[n];
#pragma unroll
    for (int i = 0; i < 4; ++i) {
#pragma unroll
      for (int r = 0; r < 4; ++r) {
        int m = m0 + wm * 64 + i * 16 + q8 * 4 + r;  // 0..8191 = b*512+s
        bf16 val = (bf16)(acc[i][j][r] + bb);
        if (mat == 2) {
          int b_ = m >> 9, s = m & 511, h = n >> 6, d = n & 63;
          vt[((size_t)(b_ * 16 + h) * 64 + d) * 512 + s] = val;
        } else if (mat == 0) {
          qw[(size_t)m * 1024 + n] = val;   // [B,S,H,DK] flat
        } else {
          kw[(size_t)m * 1024 + n] = val;
        }
      }
    }
  }
}

// ----------------------------------------------------------------- gating
// MFMA version. Token dim T = B*S*H = 131072 rows of 64 (q2d/k2d).
// Block = 128 tokens, 4 waves; wave = 32 tokens (2 m-frags).
//   fq = q2d @ Wfq   (16x16x32 MFMA, K=64, weights bf16 in LDS, B-frag = W^T)
//   fk = k2d @ Wfk
//   G  = (fq+bfq)*(fk+bfk)  -> bf16 -> LDS [tok][d] (C-layout -> A-layout)
//   M  = sigmoid(G @ Wfg + bfg)    (N=128)
//   q' = q*M[:,:64]*log2e/8 ; k' = k*M[:,64:]   (in-place RMW on own rows)
__global__ __launch_bounds__(256, 2) void k_gate(bf16* __restrict__ qw,
                                                 bf16* __restrict__ kw,
                                                 const float* __restrict__ Wfq,
                                                 const float* __restrict__ bfq,
                                                 const float* __restrict__ Wfk,
                                                 const float* __restrict__ bfk,
                                                 const float* __restrict__ Wfg,
                                                 const float* __restrict__ bfg) {
  __shared__ bf16 sWq[64 * 72];    // [n][k] = Wfq^T, pad 72
  __shared__ bf16 sWk[64 * 72];
  __shared__ bf16 sWg[128 * 72];   // [n][k] = Wfg^T
  __shared__ bf16 sG[128 * 72];    // [tok_local][d]
  __shared__ float sb[256];        // bfq[64] | bfk[64] | bfg[128]
  const int tid = threadIdx.x;

  // stage weights (transpose + cvt on the fly; global reads coalesced in n)
  for (int idx = tid; idx < 4096; idx += 256) {
    int k = idx >> 6, n = idx & 63;
    sWq[n * 72 + k] = (bf16)Wfq[k * 64 + n];
    sWk[n * 72 + k] = (bf16)Wfk[k * 64 + n];
  }
  for (int idx = tid; idx < 8192; idx += 256) {
    int k = idx >> 7, n = idx & 127;
    sWg[n * 72 + k] = (bf16)Wfg[k * 128 + n];
  }
  if (tid < 64) { sb[tid] = bfq[tid]; sb[64 + tid] = bfk[tid]; }
  if (tid < 128) sb[128 + tid] = bfg[tid];
  __syncthreads();

  const int w = tid >> 6, l = tid & 63, l4 = l & 15, q8 = l >> 4;
  const int T0 = blockIdx.x * 128;
  const int rbase = w * 32;

  // q/k A-frags straight from global (rows are contiguous 64 bf16)
  bf16x8 aq[2][2], ak[2][2];
#pragma unroll
  for (int i = 0; i < 2; ++i)
#pragma unroll
    for (int kk = 0; kk < 2; ++kk) {
      size_t off = (size_t)(T0 + rbase + i * 16 + l4) * 64 + kk * 32 + q8 * 8;
      aq[i][kk] = *(const bf16x8*)&qw[off];
      ak[i][kk] = *(const bf16x8*)&kw[off];
    }

  // GEMM1: fq, fk  (C-layout tiles 32x64 per wave)
  f32x4 fqc[2][4] = {}, fkc[2][4] = {};
#pragma unroll
  for (int j = 0; j < 4; ++j) {
    bf16x8 bq0 = *(const bf16x8*)&sWq[(j * 16 + l4) * 72 + q8 * 8];
    bf16x8 bq1 = *(const bf16x8*)&sWq[(j * 16 + l4) * 72 + 32 + q8 * 8];
    bf16x8 bk0 = *(const bf16x8*)&sWk[(j * 16 + l4) * 72 + q8 * 8];
    bf16x8 bk1 = *(const bf16x8*)&sWk[(j * 16 + l4) * 72 + 32 + q8 * 8];
#pragma unroll
    for (int i = 0; i < 2; ++i) {
      fqc[i][j] = MFMA16(aq[i][0], bq0, fqc[i][j]);
      fqc[i][j] = MFMA16(aq[i][1], bq1, fqc[i][j]);
      fkc[i][j] = MFMA16(ak[i][0], bk0, fkc[i][j]);
      fkc[i][j] = MFMA16(ak[i][1], bk1, fkc[i][j]);
    }
  }

  // G = (fq+bq)*(fk+bk) -> LDS [tok][d]  (own wave's 32 rows only)
#pragma unroll
  for (int j = 0; j < 4; ++j) {
    float bqb = sb[j * 16 + l4], bkb = sb[64 + j * 16 + l4];
#pragma unroll
    for (int i = 0; i < 2; ++i)
#pragma unroll
      for (int r = 0; r < 4; ++r) {
        int row = rbase + i * 16 + q8 * 4 + r;
        float g = (fqc[i][j][r] + bqb) * (fkc[i][j][r] + bkb);
        sG[row * 72 + j * 16 + l4] = (bf16)g;
      }
  }
  __syncthreads();

  // GEMM2: M = G @ Wfg  (N=128)
  bf16x8 ag[2][2];
#pragma unroll
  for (int i = 0; i < 2; ++i)
#pragma unroll
    for (int kk = 0; kk < 2; ++kk)
      ag[i][kk] = *(const bf16x8*)&sG[(rbase + i * 16 + l4) * 72 + kk * 32 + q8 * 8];
  f32x4 mc[2][8] = {};
#pragma unroll
  for (int jj = 0; jj < 8; ++jj) {
    bf16x8 bg0 = *(const bf16x8*)&sWg[(jj * 16 + l4) * 72 + q8 * 8];
    bf16x8 bg1 = *(const bf16x8*)&sWg[(jj * 16 + l4) * 72 + 32 + q8 * 8];
#pragma unroll
    for (int i = 0; i < 2; ++i) {
      mc[i][jj] = MFMA16(ag[i][0], bg0, mc[i][jj]);
      mc[i][jj] = MFMA16(ag[i][1], bg1, mc[i][jj]);
    }
  }

  // sigmoid + in-place apply (each (row,col) owned by exactly one lane)
  const float SC = 0.18033688011112042f;  // log2(e)/8 folded into Q
#pragma unroll
  for (int jj = 0; jj < 8; ++jj) {
    float bgb = sb[128 + jj * 16 + l4];
    bf16* base = (jj < 4) ? qw : kw;
    float scl = (jj < 4) ? SC : 1.0f;
    int col = (jj & 3) * 16 + l4;
#pragma unroll
    for (int i = 0; i < 2; ++i)
#pragma unroll
      for (int r = 0; r < 4; ++r) {
        int row = T0 + rbase + i * 16 + q8 * 4 + r;
        float m = mc[i][jj][r] + bgb;
        float sig = 1.0f / (1.0f + __expf(-m));
        size_t off = (size_t)row * 64 + col;
        base[off] = (bf16)((float)base[off] * sig * scl);
      }
  }
}

// ------------------------------------------------------------- attention
// block: 256 thr (4 waves), 128 q-rows of one (b,h); wave = 32 rows (2 m-frags).
// K/V streamed in 128-key tiles; online softmax in exp2 domain (scale in Q).
// LDS padded (+8) to break 128B-stride bank aliasing on b128 frag reads.
__global__ __launch_bounds__(256, 2) void k_attn(const bf16* __restrict__ qw,
                                                 const bf16* __restrict__ kw,
                                                 const bf16* __restrict__ vt,
                                                 float* __restrict__ out) {
  __shared__ bf16 Kt[128 * 72];       // [key][dk] padded
  __shared__ bf16 Vt[64 * 136];       // [dk][key] padded (V^T)
  __shared__ bf16 Pb[4][32 * 40];     // per-wave P chunk [32 rows][32 keys] padded
  const int tid = threadIdx.x, w = tid >> 6, l = tid & 63;
  const int l4 = l & 15, q8 = l >> 4;
  const int bx = blockIdx.x, qc = bx & 3, bh = bx >> 2;
  const int b_ = bh >> 4, h = bh & 15;
  bf16* Pw = &Pb[w][0];

  bf16x8 qf[2][2];
#pragma unroll
  for (int i = 0; i < 2; ++i)
#pragma unroll
    for (int kk = 0; kk < 2; ++kk) {
      int s = qc * 128 + w * 32 + i * 16 + l4;
      qf[i][kk] = *(const bf16x8*)
          &qw[(((size_t)b_ * 512 + s) * 16 + h) * 64 + kk * 32 + q8 * 8];
    }

  f32x4 o[2][4] = {};
  float mrun[2][4], lrun[2][4];
#pragma unroll
  for (int i = 0; i < 2; ++i)
#pragma unroll
    for (int r = 0; r < 4; ++r) { mrun[i][r] = -3.0e38f; lrun[i][r] = 0.0f; }

  for (int t = 0; t < 4; ++t) {
    __syncthreads();
#pragma unroll
    for (int i = 0; i < 4; ++i) {
      int chunk = i * 256 + tid;
      {  // K tile: straight copy, [key][dk]
        int key = chunk >> 3, c8 = chunk & 7;
        bf16x8 v = *(const bf16x8*)
            &kw[(((size_t)b_ * 512 + t * 128 + key) * 16 + h) * 64 + c8 * 8];
        *(bf16x8*)&Kt[key * 72 + c8 * 8] = v;
      }
      {  // V^T tile: straight copy from global V^T, [dk][key]
        int d = chunk >> 4, c16 = chunk & 15;
        bf16x8 v = *(const bf16x8*)
            &vt[((size_t)bh * 64 + d) * 512 + t * 128 + c16 * 8];
        *(bf16x8*)&Vt[d * 136 + c16 * 8] = v;
      }
    }
    __syncthreads();

    // scores: D[q (2x16)][key (8x16)]
    f32x4 sc[2][8];
    const f32x4 fz = {};
#pragma unroll
    for (int c = 0; c < 8; ++c) {
      bf16x8 kb0 = *(const bf16x8*)&Kt[(c * 16 + l4) * 72 + q8 * 8];
      sc[0][c] = MFMA16(qf[0][0], kb0, fz);
      sc[1][c] = MFMA16(qf[1][0], kb0, fz);
      bf16x8 kb1 = *(const bf16x8*)&Kt[(c * 16 + l4) * 72 + 32 + q8 * 8];
      sc[0][c] = MFMA16(qf[0][1], kb1, sc[0][c]);
      sc[1][c] = MFMA16(qf[1][1], kb1, sc[1][c]);
    }

    // online softmax (exp2 domain); row stats shared by 16-lane groups
#pragma unroll
    for (int i = 0; i < 2; ++i) {
      float al[4];
#pragma unroll
      for (int r = 0; r < 4; ++r) {
        float mx = sc[i][0][r];
#pragma unroll
        for (int c = 1; c < 8; ++c) mx = fmaxf(mx, sc[i][c][r]);
        mx = fmaxf(mx, __shfl_xor(mx, 1));
        mx = fmaxf(mx, __shfl_xor(mx, 2));
        mx = fmaxf(mx, __shfl_xor(mx, 4));
        mx = fmaxf(mx, __shfl_xor(mx, 8));
        float mn = fmaxf(mrun[i][r], mx);
        al[r] = exp2f(mrun[i][r] - mn);
        mrun[i][r] = mn;
        float sm = 0.0f;
#pragma unroll
        for (int c = 0; c < 8; ++c) {
          float p = exp2f(sc[i][c][r] - mn);
          sc[i][c][r] = p;
          sm += p;
        }
        sm += __shfl_xor(sm, 1); sm += __shfl_xor(sm, 2);
        sm += __shfl_xor(sm, 4); sm += __shfl_xor(sm, 8);
        lrun[i][r] = lrun[i][r] * al[r] + sm;
      }
#pragma unroll
      for (int f = 0; f < 4; ++f)
#pragma unroll
        for (int r = 0; r < 4; ++r) o[i][f][r] *= al[r];
    }

    // PV: C/D-layout P -> LDS (32-key chunks) -> A-layout frags -> MFMA
#pragma unroll
    for (int kk2 = 0; kk2 < 4; ++kk2) {
#pragma unroll
      for (int i = 0; i < 2; ++i)
#pragma unroll
        for (int cc = 0; cc < 2; ++cc) {
          int c = kk2 * 2 + cc;
#pragma unroll
          for (int r = 0; r < 4; ++r)
            Pw[(i * 16 + q8 * 4 + r) * 40 + cc * 16 + l4] = (bf16)sc[i][c][r];
        }
      bf16x8 pa0 = *(const bf16x8*)&Pw[(l4) * 40 + q8 * 8];
      bf16x8 pa1 = *(const bf16x8*)&Pw[(16 + l4) * 40 + q8 * 8];
#pragma unroll
      for (int f = 0; f < 4; ++f) {
        bf16x8 vb = *(const bf16x8*)&Vt[(f * 16 + l4) * 136 + kk2 * 32 + q8 * 8];
        o[0][f] = MFMA16(pa0, vb, o[0][f]);
        o[1][f] = MFMA16(pa1, vb, o[1][f]);
      }
    }
  }

  // epilogue: normalize, write [B,S,E] fp32
#pragma unroll
  for (int i = 0; i < 2; ++i)
#pragma unroll
    for (int r = 0; r < 4; ++r) {
      int srow = qc * 128 + w * 32 + i * 16 + q8 * 4 + r;
      float inv = 1.0f / lrun[i][r];
#pragma unroll
      for (int f = 0; f < 4; ++f)
        out[(((size_t)b_ * 512 + srow) * 16 + h) * 64 + f * 16 + l4] =
            o[i][f][r] * inv;
    }
}

// ---------------------------------------------------------------- launcher
extern "C" void kernel_launch(void* const* d_in, const int* in_sizes, int n_in,
                              void* d_out, int out_size, void* d_ws,
                              size_t ws_size, hipStream_t stream) {
  (void)in_sizes; (void)n_in; (void)out_size; (void)ws_size;
  const float* inp = (const float*)d_in[0];
  const float* Wq  = (const float*)d_in[1];
  const float* bq  = (const float*)d_in[2];
  const float* Wk  = (const float*)d_in[3];
  const float* bk  = (const float*)d_in[4];
  const float* Wv  = (const float*)d_in[5];
  const float* bv  = (const float*)d_in[6];
  const float* Wfq = (const float*)d_in[7];
  const float* bfq = (const float*)d_in[8];
  const float* Wfk = (const float*)d_in[9];
  const float* bfk = (const float*)d_in[10];
  const float* Wfg = (const float*)d_in[11];
  const float* bfg = (const float*)d_in[12];
  float* out = (float*)d_out;

  char* ws = (char*)d_ws;
  bf16* Xb = (bf16*)(ws);                                // 16 MB
  bf16* WT = (bf16*)(ws + 16777216);                     // 6 MB (3x W^T)
  bf16* qw = (bf16*)(ws + 16777216 + 6291456);           // 16 MB [B,S,H,DK]
  bf16* kw = qw + 8388608;                               // 16 MB
  bf16* vt = kw + 8388608;                               // 16 MB [B,H,DK,S]

  k_conv_inp<<<8192, 256, 0, stream>>>(inp, Xb);
  k_wt<<<dim3(32, 32, 3), 256, 0, stream>>>(Wq, Wk, Wv, WT);
  k_proj<<<dim3(64, 24), 256, 0, stream>>>(Xb, WT, bq, bk, bv, qw, kw, vt);
  k_gate<<<1024, 256, 0, stream>>>(qw, kw, Wfq, bfq, Wfk, bfk, Wfg, bfg);
  k_attn<<<1024, 256, 0, stream>>>(qw, kw, vt, out);
}

// Round 3
// 271.747 us; speedup vs baseline: 1.3786x; 1.0104x over previous
//
#include <hip/hip_runtime.h>

// GatedQueryAttLayer on MI355X (gfx950)
// B=16, S=512, E=1024, H=16, DK=64
// Pipeline: conv(inp->bf16) ; transpose+cvt(Wq/Wk/Wv -> W^T bf16) ;
//           fused QKV bf16-MFMA GEMM ; MFMA gating ; flash attention.
// Workspace: 70 MB.

typedef __bf16 bf16;
typedef __bf16 bf16x8 __attribute__((ext_vector_type(8)));
typedef __bf16 bf16x4 __attribute__((ext_vector_type(4)));
typedef float  f32x4  __attribute__((ext_vector_type(4)));

#define MFMA16(a,b,c) __builtin_amdgcn_mfma_f32_16x16x32_bf16((a),(b),(c),0,0,0)

// async global->LDS, 16B per lane; LDS dest is wave-uniform base + lane*16,
// so lds layout must be linear in lane order. The global source address is
// per-lane free -> we use that freedom for an XOR bank swizzle.
#define GLL16(gp, lp)                                                          \
  __builtin_amdgcn_global_load_lds(                                            \
      (__attribute__((address_space(1))) void*)(void*)(gp),                    \
      (__attribute__((address_space(3))) void*)(lp), 16, 0, 0)

// ---------------------------------------------------------------- conv inp
__global__ __launch_bounds__(256) void k_conv_inp(const float* __restrict__ in,
                                                  bf16* __restrict__ out) {
  int i = blockIdx.x * 256 + threadIdx.x;   // 4 elems per thread
  float4 v = ((const float4*)in)[i];
  bf16x4 o;
  o[0] = (bf16)v.x; o[1] = (bf16)v.y; o[2] = (bf16)v.z; o[3] = (bf16)v.w;
  ((bf16x4*)out)[i] = o;
}

// ------------------------------------------- weight transpose + cvt to bf16
// W[k][n] fp32 (1024x1024) -> WT[n][k] bf16, for Wq/Wk/Wv (blockIdx.z)
__global__ __launch_bounds__(256) void k_wt(const float* __restrict__ Wq,
                                            const float* __restrict__ Wk,
                                            const float* __restrict__ Wv,
                                            bf16* __restrict__ WT) {
  __shared__ float tile[32][33];
  const int mat = blockIdx.z;
  const float* W = (mat == 0) ? Wq : ((mat == 1) ? Wk : Wv);
  bf16* O = WT + (size_t)mat * (1024 * 1024);
  const int kb = blockIdx.x, nb = blockIdx.y;
  const int t = threadIdx.x, tr = t >> 3, tc = (t & 7) * 4;
  float4 v = *(const float4*)&W[(size_t)(kb * 32 + tr) * 1024 + nb * 32 + tc];
  tile[tr][tc] = v.x; tile[tr][tc + 1] = v.y;
  tile[tr][tc + 2] = v.z; tile[tr][tc + 3] = v.w;
  __syncthreads();
  bf16x4 o;
  o[0] = (bf16)tile[tc][tr];     o[1] = (bf16)tile[tc + 1][tr];
  o[2] = (bf16)tile[tc + 2][tr]; o[3] = (bf16)tile[tc + 3][tr];
  *(bf16x4*)&O[(size_t)(nb * 32 + tr) * 1024 + kb * 32 + tc] = o;
}

// -------------------------------------------------- fused QKV projection GEMM
// X[8192][1024] bf16 @ W^T -> q/k: [B,S,H,DK] bf16 ; v: [B,H,DK,S] bf16 (V^T)
// BM=BN=128, BK=32, 256 thr (4 waves, 2x2 of 64x64), 16x16x32 MFMA.
// LDS tiles XOR-swizzled: slot (row,c) holds global chunk c^f(row),
// f(row)=(row+(row>>2))&3 -> fragment ds_read_b128 is 2-way (free) instead
// of 8-way conflicted. MFMA operands SWAPPED (b,a) so C is transposed:
// lanes <-> m, regs <-> 4 consecutive n -> vectorized/coalesced stores.
__global__ __launch_bounds__(256) void k_proj(const bf16* __restrict__ X,
                                              const bf16* __restrict__ WT,
                                              const float* __restrict__ bq,
                                              const float* __restrict__ bk,
                                              const float* __restrict__ bv,
                                              bf16* __restrict__ qw,
                                              bf16* __restrict__ kw,
                                              bf16* __restrict__ vt) {
  __shared__ bf16 As[128 * 32];
  __shared__ bf16 Bs[128 * 32];
  const int tid = threadIdx.x;
  const int m0 = blockIdx.x * 128;
  const int by = blockIdx.y;
  const int mat = by >> 3;             // 0=q,1=k,2=v
  const int n0 = (by & 7) * 128;       // within this matrix's 1024 cols
  const bf16* Wt = WT + (size_t)mat * (1024 * 1024);
  const float* bias = (mat == 0) ? bq : ((mat == 1) ? bk : bv);
  const int l = tid & 63, w = tid >> 6;
  const int wm = w >> 1, wn = w & 1;
  const int l4 = l & 15, q8 = l >> 4;

  // reader-side swizzled chunk indices (row -> which LDS chunk holds k-chunk q8)
  const int rowa = wm * 64 + l4;   // a-frag rows are rowa + i*16; f inv. to +16*i
  const int rowb = wn * 64 + l4;
  const int ca = q8 ^ ((rowa + (rowa >> 2)) & 3);  // (row+16i)>>2 adds mult of 4
  const int cb = q8 ^ ((rowb + (rowb >> 2)) & 3);

  f32x4 acc[4][4] = {};
  for (int kt = 0; kt < 1024; kt += 32) {
    __syncthreads();
#pragma unroll
    for (int i = 0; i < 2; ++i) {
      int chunk = i * 256 + tid;                       // 8 bf16 per chunk
      int srow = chunk >> 2, cs = chunk & 3;
      int cg = cs ^ ((srow + (srow >> 2)) & 3);        // fetch permuted chunk
      GLL16(X  + (size_t)(m0 + srow) * 1024 + kt + cg * 8, As + chunk * 8);
      GLL16(Wt + (size_t)(n0 + srow) * 1024 + kt + cg * 8, Bs + chunk * 8);
    }
    __syncthreads();
    bf16x8 a[4], b[4];
#pragma unroll
    for (int i = 0; i < 4; ++i)
      a[i] = *(const bf16x8*)&As[(rowa + i * 16) * 32 + ca * 8];
#pragma unroll
    for (int j = 0; j < 4; ++j)
      b[j] = *(const bf16x8*)&Bs[(rowb + j * 16) * 32 + cb * 8];
#pragma unroll
    for (int i = 0; i < 4; ++i)
#pragma unroll
      for (int j = 0; j < 4; ++j)
        acc[i][j] = MFMA16(b[j], a[i], acc[i][j]);   // swapped: C transposed
  }
  // epilogue: lanes <-> m (l4), regs <-> n (q8*4+r)
#pragma unroll
  for (int i = 0; i < 4; ++i) {
    int m = m0 + wm * 64 + i * 16 + l4;    // 0..8191 = b*512+s
    int b_ = m >> 9, s = m & 511;
#pragma unroll
    for (int j = 0; j < 4; ++j) {
      int nb = n0 + wn * 64 + j * 16 + q8 * 4;   // 4 consecutive n
      if (mat == 2) {
#pragma unroll
        for (int r = 0; r < 4; ++r) {
          int n = nb + r, h = n >> 6, d = n & 63;
          vt[((size_t)(b_ * 16 + h) * 64 + d) * 512 + s] =
              (bf16)(acc[i][j][r] + bias[n]);
        }
      } else {
        float4 bb = *(const float4*)&bias[nb];
        bf16x4 o;
        o[0] = (bf16)(acc[i][j][0] + bb.x);
        o[1] = (bf16)(acc[i][j][1] + bb.y);
        o[2] = (bf16)(acc[i][j][2] + bb.z);
        o[3] = (bf16)(acc[i][j][3] + bb.w);
        bf16* dst = (mat == 0) ? qw : kw;
        *(bf16x4*)&dst[(size_t)m * 1024 + nb] = o;
      }
    }
  }
}

// ----------------------------------------------------------------- gating
// MFMA version. Token dim T = B*S*H = 131072 rows of 64 (q2d/k2d).
// Block = 128 tokens, 4 waves; wave = 32 tokens (2 m-frags).
//   fq = q2d @ Wfq   (16x16x32 MFMA, K=64, weights bf16 in LDS, B-frag = W^T)
//   fk = k2d @ Wfk
//   G  = (fq+bfq)*(fk+bfk)  -> bf16 -> LDS [tok][d] (C-layout -> A-layout)
//   M  = sigmoid(G @ Wfg + bfg)    (N=128)
//   q' = q*M[:,:64]*log2e/8 ; k' = k*M[:,64:]   (in-place RMW on own rows)
__global__ __launch_bounds__(256, 2) void k_gate(bf16* __restrict__ qw,
                                                 bf16* __restrict__ kw,
                                                 const float* __restrict__ Wfq,
                                                 const float* __restrict__ bfq,
                                                 const float* __restrict__ Wfk,
                                                 const float* __restrict__ bfk,
                                                 const float* __restrict__ Wfg,
                                                 const float* __restrict__ bfg) {
  __shared__ bf16 sWq[64 * 72];    // [n][k] = Wfq^T, pad 72
  __shared__ bf16 sWk[64 * 72];
  __shared__ bf16 sWg[128 * 72];   // [n][k] = Wfg^T
  __shared__ bf16 sG[128 * 72];    // [tok_local][d]
  __shared__ float sb[256];        // bfq[64] | bfk[64] | bfg[128]
  const int tid = threadIdx.x;

  // stage weights (transpose + cvt on the fly; global reads coalesced in n)
  for (int idx = tid; idx < 4096; idx += 256) {
    int k = idx >> 6, n = idx & 63;
    sWq[n * 72 + k] = (bf16)Wfq[k * 64 + n];
    sWk[n * 72 + k] = (bf16)Wfk[k * 64 + n];
  }
  for (int idx = tid; idx < 8192; idx += 256) {
    int k = idx >> 7, n = idx & 127;
    sWg[n * 72 + k] = (bf16)Wfg[k * 128 + n];
  }
  if (tid < 64) { sb[tid] = bfq[tid]; sb[64 + tid] = bfk[tid]; }
  if (tid < 128) sb[128 + tid] = bfg[tid];
  __syncthreads();

  const int w = tid >> 6, l = tid & 63, l4 = l & 15, q8 = l >> 4;
  const int T0 = blockIdx.x * 128;
  const int rbase = w * 32;

  // q/k A-frags straight from global (rows are contiguous 64 bf16)
  bf16x8 aq[2][2], ak[2][2];
#pragma unroll
  for (int i = 0; i < 2; ++i)
#pragma unroll
    for (int kk = 0; kk < 2; ++kk) {
      size_t off = (size_t)(T0 + rbase + i * 16 + l4) * 64 + kk * 32 + q8 * 8;
      aq[i][kk] = *(const bf16x8*)&qw[off];
      ak[i][kk] = *(const bf16x8*)&kw[off];
    }

  // GEMM1: fq, fk  (C-layout tiles 32x64 per wave)
  f32x4 fqc[2][4] = {}, fkc[2][4] = {};
#pragma unroll
  for (int j = 0; j < 4; ++j) {
    bf16x8 bq0 = *(const bf16x8*)&sWq[(j * 16 + l4) * 72 + q8 * 8];
    bf16x8 bq1 = *(const bf16x8*)&sWq[(j * 16 + l4) * 72 + 32 + q8 * 8];
    bf16x8 bk0 = *(const bf16x8*)&sWk[(j * 16 + l4) * 72 + q8 * 8];
    bf16x8 bk1 = *(const bf16x8*)&sWk[(j * 16 + l4) * 72 + 32 + q8 * 8];
#pragma unroll
    for (int i = 0; i < 2; ++i) {
      fqc[i][j] = MFMA16(aq[i][0], bq0, fqc[i][j]);
      fqc[i][j] = MFMA16(aq[i][1], bq1, fqc[i][j]);
      fkc[i][j] = MFMA16(ak[i][0], bk0, fkc[i][j]);
      fkc[i][j] = MFMA16(ak[i][1], bk1, fkc[i][j]);
    }
  }

  // G = (fq+bq)*(fk+bk) -> LDS [tok][d]  (own wave's 32 rows only)
#pragma unroll
  for (int j = 0; j < 4; ++j) {
    float bqb = sb[j * 16 + l4], bkb = sb[64 + j * 16 + l4];
#pragma unroll
    for (int i = 0; i < 2; ++i)
#pragma unroll
      for (int r = 0; r < 4; ++r) {
        int row = rbase + i * 16 + q8 * 4 + r;
        float g = (fqc[i][j][r] + bqb) * (fkc[i][j][r] + bkb);
        sG[row * 72 + j * 16 + l4] = (bf16)g;
      }
  }
  __syncthreads();

  // GEMM2: M = G @ Wfg  (N=128)
  bf16x8 ag[2][2];
#pragma unroll
  for (int i = 0; i < 2; ++i)
#pragma unroll
    for (int kk = 0; kk < 2; ++kk)
      ag[i][kk] = *(const bf16x8*)&sG[(rbase + i * 16 + l4) * 72 + kk * 32 + q8 * 8];
  f32x4 mc[2][8] = {};
#pragma unroll
  for (int jj = 0; jj < 8; ++jj) {
    bf16x8 bg0 = *(const bf16x8*)&sWg[(jj * 16 + l4) * 72 + q8 * 8];
    bf16x8 bg1 = *(const bf16x8*)&sWg[(jj * 16 + l4) * 72 + 32 + q8 * 8];
#pragma unroll
    for (int i = 0; i < 2; ++i) {
      mc[i][jj] = MFMA16(ag[i][0], bg0, mc[i][jj]);
      mc[i][jj] = MFMA16(ag[i][1], bg1, mc[i][jj]);
    }
  }

  // sigmoid + in-place apply (each (row,col) owned by exactly one lane)
  const float SC = 0.18033688011112042f;  // log2(e)/8 folded into Q
#pragma unroll
  for (int jj = 0; jj < 8; ++jj) {
    float bgb = sb[128 + jj * 16 + l4];
    bf16* base = (jj < 4) ? qw : kw;
    float scl = (jj < 4) ? SC : 1.0f;
    int col = (jj & 3) * 16 + l4;
#pragma unroll
    for (int i = 0; i < 2; ++i)
#pragma unroll
      for (int r = 0; r < 4; ++r) {
        int row = T0 + rbase + i * 16 + q8 * 4 + r;
        float m = mc[i][jj][r] + bgb;
        float sig = 1.0f / (1.0f + __expf(-m));
        size_t off = (size_t)row * 64 + col;
        base[off] = (bf16)((float)base[off] * sig * scl);
      }
  }
}

// ------------------------------------------------------------- attention
// block: 256 thr (4 waves), 128 q-rows of one (b,h); wave = 32 rows (2 m-frags).
// K/V streamed in 128-key tiles; online softmax in exp2 domain (scale in Q).
// LDS padded (+8) to break 128B-stride bank aliasing on b128 frag reads.
__global__ __launch_bounds__(256, 2) void k_attn(const bf16* __restrict__ qw,
                                                 const bf16* __restrict__ kw,
                                                 const bf16* __restrict__ vt,
                                                 float* __restrict__ out) {
  __shared__ bf16 Kt[128 * 72];       // [key][dk] padded
  __shared__ bf16 Vt[64 * 136];       // [dk][key] padded (V^T)
  __shared__ bf16 Pb[4][32 * 40];     // per-wave P chunk [32 rows][32 keys] padded
  const int tid = threadIdx.x, w = tid >> 6, l = tid & 63;
  const int l4 = l & 15, q8 = l >> 4;
  const int bx = blockIdx.x, qc = bx & 3, bh = bx >> 2;
  const int b_ = bh >> 4, h = bh & 15;
  bf16* Pw = &Pb[w][0];

  bf16x8 qf[2][2];
#pragma unroll
  for (int i = 0; i < 2; ++i)
#pragma unroll
    for (int kk = 0; kk < 2; ++kk) {
      int s = qc * 128 + w * 32 + i * 16 + l4;
      qf[i][kk] = *(const bf16x8*)
          &qw[(((size_t)b_ * 512 + s) * 16 + h) * 64 + kk * 32 + q8 * 8];
    }

  f32x4 o[2][4] = {};
  float mrun[2][4], lrun[2][4];
#pragma unroll
  for (int i = 0; i < 2; ++i)
#pragma unroll
    for (int r = 0; r < 4; ++r) { mrun[i][r] = -3.0e38f; lrun[i][r] = 0.0f; }

  for (int t = 0; t < 4; ++t) {
    __syncthreads();
#pragma unroll
    for (int i = 0; i < 4; ++i) {
      int chunk = i * 256 + tid;
      {  // K tile: straight copy, [key][dk]
        int key = chunk >> 3, c8 = chunk & 7;
        bf16x8 v = *(const bf16x8*)
            &kw[(((size_t)b_ * 512 + t * 128 + key) * 16 + h) * 64 + c8 * 8];
        *(bf16x8*)&Kt[key * 72 + c8 * 8] = v;
      }
      {  // V^T tile: straight copy from global V^T, [dk][key]
        int d = chunk >> 4, c16 = chunk & 15;
        bf16x8 v = *(const bf16x8*)
            &vt[((size_t)bh * 64 + d) * 512 + t * 128 + c16 * 8];
        *(bf16x8*)&Vt[d * 136 + c16 * 8] = v;
      }
    }
    __syncthreads();

    // scores: D[q (2x16)][key (8x16)]
    f32x4 sc[2][8];
    const f32x4 fz = {};
#pragma unroll
    for (int c = 0; c < 8; ++c) {
      bf16x8 kb0 = *(const bf16x8*)&Kt[(c * 16 + l4) * 72 + q8 * 8];
      sc[0][c] = MFMA16(qf[0][0], kb0, fz);
      sc[1][c] = MFMA16(qf[1][0], kb0, fz);
      bf16x8 kb1 = *(const bf16x8*)&Kt[(c * 16 + l4) * 72 + 32 + q8 * 8];
      sc[0][c] = MFMA16(qf[0][1], kb1, sc[0][c]);
      sc[1][c] = MFMA16(qf[1][1], kb1, sc[1][c]);
    }

    // online softmax (exp2 domain); row stats shared by 16-lane groups
#pragma unroll
    for (int i = 0; i < 2; ++i) {
      float al[4];
#pragma unroll
      for (int r = 0; r < 4; ++r) {
        float mx = sc[i][0][r];
#pragma unroll
        for (int c = 1; c < 8; ++c) mx = fmaxf(mx, sc[i][c][r]);
        mx = fmaxf(mx, __shfl_xor(mx, 1));
        mx = fmaxf(mx, __shfl_xor(mx, 2));
        mx = fmaxf(mx, __shfl_xor(mx, 4));
        mx = fmaxf(mx, __shfl_xor(mx, 8));
        float mn = fmaxf(mrun[i][r], mx);
        al[r] = exp2f(mrun[i][r] - mn);
        mrun[i][r] = mn;
        float sm = 0.0f;
#pragma unroll
        for (int c = 0; c < 8; ++c) {
          float p = exp2f(sc[i][c][r] - mn);
          sc[i][c][r] = p;
          sm += p;
        }
        sm += __shfl_xor(sm, 1); sm += __shfl_xor(sm, 2);
        sm += __shfl_xor(sm, 4); sm += __shfl_xor(sm, 8);
        lrun[i][r] = lrun[i][r] * al[r] + sm;
      }
#pragma unroll
      for (int f = 0; f < 4; ++f)
#pragma unroll
        for (int r = 0; r < 4; ++r) o[i][f][r] *= al[r];
    }

    // PV: C/D-layout P -> LDS (32-key chunks) -> A-layout frags -> MFMA
#pragma unroll
    for (int kk2 = 0; kk2 < 4; ++kk2) {
#pragma unroll
      for (int i = 0; i < 2; ++i)
#pragma unroll
        for (int cc = 0; cc < 2; ++cc) {
          int c = kk2 * 2 + cc;
#pragma unroll
          for (int r = 0; r < 4; ++r)
            Pw[(i * 16 + q8 * 4 + r) * 40 + cc * 16 + l4] = (bf16)sc[i][c][r];
        }
      bf16x8 pa0 = *(const bf16x8*)&Pw[(l4) * 40 + q8 * 8];
      bf16x8 pa1 = *(const bf16x8*)&Pw[(16 + l4) * 40 + q8 * 8];
#pragma unroll
      for (int f = 0; f < 4; ++f) {
        bf16x8 vb = *(const bf16x8*)&Vt[(f * 16 + l4) * 136 + kk2 * 32 + q8 * 8];
        o[0][f] = MFMA16(pa0, vb, o[0][f]);
        o[1][f] = MFMA16(pa1, vb, o[1][f]);
      }
    }
  }

  // epilogue: normalize, write [B,S,E] fp32
#pragma unroll
  for (int i = 0; i < 2; ++i)
#pragma unroll
    for (int r = 0; r < 4; ++r) {
      int srow = qc * 128 + w * 32 + i * 16 + q8 * 4 + r;
      float inv = 1.0f / lrun[i][r];
#pragma unroll
      for (int f = 0; f < 4; ++f)
        out[(((size_t)b_ * 512 + srow) * 16 + h) * 64 + f * 16 + l4] =
            o[i][f][r] * inv;
    }
}

// ---------------------------------------------------------------- launcher
extern "C" void kernel_launch(void* const* d_in, const int* in_sizes, int n_in,
                              void* d_out, int out_size, void* d_ws,
                              size_t ws_size, hipStream_t stream) {
  (void)in_sizes; (void)n_in; (void)out_size; (void)ws_size;
  const float* inp = (const float*)d_in[0];
  const float* Wq  = (const float*)d_in[1];
  const float* bq  = (const float*)d_in[2];
  const float* Wk  = (const float*)d_in[3];
  const float* bk  = (const float*)d_in[4];
  const float* Wv  = (const float*)d_in[5];
  const float* bv  = (const float*)d_in[6];
  const float* Wfq = (const float*)d_in[7];
  const float* bfq = (const float*)d_in[8];
  const float* Wfk = (const float*)d_in[9];
  const float* bfk = (const float*)d_in[10];
  const float* Wfg = (const float*)d_in[11];
  const float* bfg = (const float*)d_in[12];
  float* out = (float*)d_out;

  char* ws = (char*)d_ws;
  bf16* Xb = (bf16*)(ws);                                // 16 MB
  bf16* WT = (bf16*)(ws + 16777216);                     // 6 MB (3x W^T)
  bf16* qw = (bf16*)(ws + 16777216 + 6291456);           // 16 MB [B,S,H,DK]
  bf16* kw = qw + 8388608;                               // 16 MB
  bf16* vt = kw + 8388608;                               // 16 MB [B,H,DK,S]

  k_conv_inp<<<8192, 256, 0, stream>>>(inp, Xb);
  k_wt<<<dim3(32, 32, 3), 256, 0, stream>>>(Wq, Wk, Wv, WT);
  k_proj<<<dim3(64, 24), 256, 0, stream>>>(Xb, WT, bq, bk, bv, qw, kw, vt);
  k_gate<<<1024, 256, 0, stream>>>(qw, kw, Wfq, bfq, Wfk, bfk, Wfg, bfg);
  k_attn<<<1024, 256, 0, stream>>>(qw, kw, vt, out);
}

// Round 4
// 271.095 us; speedup vs baseline: 1.3819x; 1.0024x over previous
//
#include <hip/hip_runtime.h>

// GatedQueryAttLayer on MI355X (gfx950)
// B=16, S=512, E=1024, H=16, DK=64
// Pipeline: conv(inp->bf16) ; transpose+cvt(Wq/Wk/Wv -> W^T bf16) ;
//           fused QKV bf16-MFMA GEMM (double-buffered) ; MFMA gating ;
//           flash attention.
// Workspace: 70 MB.

typedef __bf16 bf16;
typedef __bf16 bf16x8 __attribute__((ext_vector_type(8)));
typedef __bf16 bf16x4 __attribute__((ext_vector_type(4)));
typedef float  f32x4  __attribute__((ext_vector_type(4)));

#define MFMA16(a,b,c) __builtin_amdgcn_mfma_f32_16x16x32_bf16((a),(b),(c),0,0,0)

// async global->LDS, 16B per lane; LDS dest is wave-uniform base + lane*16,
// so lds layout must be linear in lane order (it is, below).
#define GLL16(gp, lp)                                                          \
  __builtin_amdgcn_global_load_lds(                                            \
      (__attribute__((address_space(1))) void*)(void*)(gp),                    \
      (__attribute__((address_space(3))) void*)(lp), 16, 0, 0)

// ---------------------------------------------------------------- conv inp
__global__ __launch_bounds__(256) void k_conv_inp(const float* __restrict__ in,
                                                  bf16* __restrict__ out) {
  int i = blockIdx.x * 256 + threadIdx.x;   // 4 elems per thread
  float4 v = ((const float4*)in)[i];
  bf16x4 o;
  o[0] = (bf16)v.x; o[1] = (bf16)v.y; o[2] = (bf16)v.z; o[3] = (bf16)v.w;
  ((bf16x4*)out)[i] = o;
}

// ------------------------------------------- weight transpose + cvt to bf16
// W[k][n] fp32 (1024x1024) -> WT[n][k] bf16, for Wq/Wk/Wv (blockIdx.z)
__global__ __launch_bounds__(256) void k_wt(const float* __restrict__ Wq,
                                            const float* __restrict__ Wk,
                                            const float* __restrict__ Wv,
                                            bf16* __restrict__ WT) {
  __shared__ float tile[32][33];
  const int mat = blockIdx.z;
  const float* W = (mat == 0) ? Wq : ((mat == 1) ? Wk : Wv);
  bf16* O = WT + (size_t)mat * (1024 * 1024);
  const int kb = blockIdx.x, nb = blockIdx.y;
  const int t = threadIdx.x, tr = t >> 3, tc = (t & 7) * 4;
  float4 v = *(const float4*)&W[(size_t)(kb * 32 + tr) * 1024 + nb * 32 + tc];
  tile[tr][tc] = v.x; tile[tr][tc + 1] = v.y;
  tile[tr][tc + 2] = v.z; tile[tr][tc + 3] = v.w;
  __syncthreads();
  bf16x4 o;
  o[0] = (bf16)tile[tc][tr];     o[1] = (bf16)tile[tc + 1][tr];
  o[2] = (bf16)tile[tc + 2][tr]; o[3] = (bf16)tile[tc + 3][tr];
  *(bf16x4*)&O[(size_t)(nb * 32 + tr) * 1024 + kb * 32 + tc] = o;
}

// -------------------------------------------------- fused QKV projection GEMM
// X[8192][1024] bf16 @ W^T -> q/k: [B,S,H,DK] bf16 ; v: [B,H,DK,S] bf16 (V^T)
// BM=BN=128, BK=32, 256 thr (4 waves, 2x2 of 64x64), 16x16x32 MFMA.
// DOUBLE-BUFFERED: one __syncthreads per K-iter; prefetch of tile t+1 issued
// right after the barrier so its vmcnt drain overlaps the whole compute phase.
// MFMA operands swapped (b,a) so C is transposed: lanes<->m, regs<->4
// consecutive n -> vectorized q/k stores, lane-contiguous V^T stores.
// Note: SQ_LDS_BANK_CONFLICT ~6.29e6 here is inherent ds_read_b128
// multi-cycle return (8 lanes per 4-bank group = structural floor), not
// fixable aliasing — verified by a swizzle A/B in rounds 2/3 (identical count).
__global__ __launch_bounds__(256) void k_proj(const bf16* __restrict__ X,
                                              const bf16* __restrict__ WT,
                                              const float* __restrict__ bq,
                                              const float* __restrict__ bk,
                                              const float* __restrict__ bv,
                                              bf16* __restrict__ qw,
                                              bf16* __restrict__ kw,
                                              bf16* __restrict__ vt) {
  __shared__ bf16 As[2][128 * 32];
  __shared__ bf16 Bs[2][128 * 32];
  const int tid = threadIdx.x;
  const int m0 = blockIdx.x * 128;
  const int by = blockIdx.y;
  const int mat = by >> 3;             // 0=q,1=k,2=v
  const int n0 = (by & 7) * 128;       // within this matrix's 1024 cols
  const bf16* Wt = WT + (size_t)mat * (1024 * 1024);
  const float* bias = (mat == 0) ? bq : ((mat == 1) ? bk : bv);
  const int l = tid & 63, w = tid >> 6;
  const int wm = w >> 1, wn = w & 1;
  const int l4 = l & 15, q8 = l >> 4;
  const int rowa = wm * 64 + l4;
  const int rowb = wn * 64 + l4;

  // fixed per-thread staging slots: chunk c covers row c>>2, k-chunk c&3
  const int c0 = tid, c1 = 256 + tid;
  const bf16* gA0 = X  + (size_t)(m0 + (c0 >> 2)) * 1024 + (c0 & 3) * 8;
  const bf16* gB0 = Wt + (size_t)(n0 + (c0 >> 2)) * 1024 + (c0 & 3) * 8;
  const bf16* gA1 = X  + (size_t)(m0 + (c1 >> 2)) * 1024 + (c1 & 3) * 8;
  const bf16* gB1 = Wt + (size_t)(n0 + (c1 >> 2)) * 1024 + (c1 & 3) * 8;

  // prologue: stage tile 0 into buffer 0
  GLL16(gA0, &As[0][c0 * 8]);
  GLL16(gB0, &Bs[0][c0 * 8]);
  GLL16(gA1, &As[0][c1 * 8]);
  GLL16(gB1, &Bs[0][c1 * 8]);

  f32x4 acc[4][4] = {};
  for (int t = 0; t < 32; ++t) {
    __syncthreads();                    // publishes tile t (drains its vmcnt)
    if (t + 1 < 32) {                   // prefetch tile t+1 into other buffer
      int nb_ = (t + 1) & 1, kt = (t + 1) * 32;
      GLL16(gA0 + kt, &As[nb_][c0 * 8]);
      GLL16(gB0 + kt, &Bs[nb_][c0 * 8]);
      GLL16(gA1 + kt, &As[nb_][c1 * 8]);
      GLL16(gB1 + kt, &Bs[nb_][c1 * 8]);
    }
    const bf16* Ab = As[t & 1];
    const bf16* Bb = Bs[t & 1];
    bf16x8 a[4], b[4];
#pragma unroll
    for (int i = 0; i < 4; ++i)
      a[i] = *(const bf16x8*)&Ab[(rowa + i * 16) * 32 + q8 * 8];
#pragma unroll
    for (int j = 0; j < 4; ++j)
      b[j] = *(const bf16x8*)&Bb[(rowb + j * 16) * 32 + q8 * 8];
#pragma unroll
    for (int i = 0; i < 4; ++i)
#pragma unroll
      for (int j = 0; j < 4; ++j)
        acc[i][j] = MFMA16(b[j], a[i], acc[i][j]);   // swapped: C transposed
  }
  // epilogue: lanes <-> m (l4), regs <-> n (q8*4+r)
#pragma unroll
  for (int i = 0; i < 4; ++i) {
    int m = m0 + wm * 64 + i * 16 + l4;    // 0..8191 = b*512+s
    int b_ = m >> 9, s = m & 511;
#pragma unroll
    for (int j = 0; j < 4; ++j) {
      int nb = n0 + wn * 64 + j * 16 + q8 * 4;   // 4 consecutive n
      if (mat == 2) {
#pragma unroll
        for (int r = 0; r < 4; ++r) {
          int n = nb + r, h = n >> 6, d = n & 63;
          vt[((size_t)(b_ * 16 + h) * 64 + d) * 512 + s] =
              (bf16)(acc[i][j][r] + bias[n]);
        }
      } else {
        float4 bb = *(const float4*)&bias[nb];
        bf16x4 o;
        o[0] = (bf16)(acc[i][j][0] + bb.x);
        o[1] = (bf16)(acc[i][j][1] + bb.y);
        o[2] = (bf16)(acc[i][j][2] + bb.z);
        o[3] = (bf16)(acc[i][j][3] + bb.w);
        bf16* dst = (mat == 0) ? qw : kw;
        *(bf16x4*)&dst[(size_t)m * 1024 + nb] = o;
      }
    }
  }
}

// ----------------------------------------------------------------- gating
// MFMA version. Token dim T = B*S*H = 131072 rows of 64 (q2d/k2d).
// Block = 128 tokens, 4 waves; wave = 32 tokens (2 m-frags).
//   fq = q2d @ Wfq   (16x16x32 MFMA, K=64, weights bf16 in LDS, B-frag = W^T)
//   fk = k2d @ Wfk
//   G  = (fq+bfq)*(fk+bfk)  -> bf16 -> LDS [tok][d] (C-layout -> A-layout)
//   M  = sigmoid(G @ Wfg + bfg)    (N=128)
//   q' = q*M[:,:64]*log2e/8 ; k' = k*M[:,64:]   (in-place RMW on own rows)
__global__ __launch_bounds__(256, 2) void k_gate(bf16* __restrict__ qw,
                                                 bf16* __restrict__ kw,
                                                 const float* __restrict__ Wfq,
                                                 const float* __restrict__ bfq,
                                                 const float* __restrict__ Wfk,
                                                 const float* __restrict__ bfk,
                                                 const float* __restrict__ Wfg,
                                                 const float* __restrict__ bfg) {
  __shared__ bf16 sWq[64 * 72];    // [n][k] = Wfq^T, pad 72
  __shared__ bf16 sWk[64 * 72];
  __shared__ bf16 sWg[128 * 72];   // [n][k] = Wfg^T
  __shared__ bf16 sG[128 * 72];    // [tok_local][d]
  __shared__ float sb[256];        // bfq[64] | bfk[64] | bfg[128]
  const int tid = threadIdx.x;

  // stage weights (transpose + cvt on the fly; global reads coalesced in n)
  for (int idx = tid; idx < 4096; idx += 256) {
    int k = idx >> 6, n = idx & 63;
    sWq[n * 72 + k] = (bf16)Wfq[k * 64 + n];
    sWk[n * 72 + k] = (bf16)Wfk[k * 64 + n];
  }
  for (int idx = tid; idx < 8192; idx += 256) {
    int k = idx >> 7, n = idx & 127;
    sWg[n * 72 + k] = (bf16)Wfg[k * 128 + n];
  }
  if (tid < 64) { sb[tid] = bfq[tid]; sb[64 + tid] = bfk[tid]; }
  if (tid < 128) sb[128 + tid] = bfg[tid];
  __syncthreads();

  const int w = tid >> 6, l = tid & 63, l4 = l & 15, q8 = l >> 4;
  const int T0 = blockIdx.x * 128;
  const int rbase = w * 32;

  // q/k A-frags straight from global (rows are contiguous 64 bf16)
  bf16x8 aq[2][2], ak[2][2];
#pragma unroll
  for (int i = 0; i < 2; ++i)
#pragma unroll
    for (int kk = 0; kk < 2; ++kk) {
      size_t off = (size_t)(T0 + rbase + i * 16 + l4) * 64 + kk * 32 + q8 * 8;
      aq[i][kk] = *(const bf16x8*)&qw[off];
      ak[i][kk] = *(const bf16x8*)&kw[off];
    }

  // GEMM1: fq, fk  (C-layout tiles 32x64 per wave)
  f32x4 fqc[2][4] = {}, fkc[2][4] = {};
#pragma unroll
  for (int j = 0; j < 4; ++j) {
    bf16x8 bq0 = *(const bf16x8*)&sWq[(j * 16 + l4) * 72 + q8 * 8];
    bf16x8 bq1 = *(const bf16x8*)&sWq[(j * 16 + l4) * 72 + 32 + q8 * 8];
    bf16x8 bk0 = *(const bf16x8*)&sWk[(j * 16 + l4) * 72 + q8 * 8];
    bf16x8 bk1 = *(const bf16x8*)&sWk[(j * 16 + l4) * 72 + 32 + q8 * 8];
#pragma unroll
    for (int i = 0; i < 2; ++i) {
      fqc[i][j] = MFMA16(aq[i][0], bq0, fqc[i][j]);
      fqc[i][j] = MFMA16(aq[i][1], bq1, fqc[i][j]);
      fkc[i][j] = MFMA16(ak[i][0], bk0, fkc[i][j]);
      fkc[i][j] = MFMA16(ak[i][1], bk1, fkc[i][j]);
    }
  }

  // G = (fq+bq)*(fk+bk) -> LDS [tok][d]  (own wave's 32 rows only)
#pragma unroll
  for (int j = 0; j < 4; ++j) {
    float bqb = sb[j * 16 + l4], bkb = sb[64 + j * 16 + l4];
#pragma unroll
    for (int i = 0; i < 2; ++i)
#pragma unroll
      for (int r = 0; r < 4; ++r) {
        int row = rbase + i * 16 + q8 * 4 + r;
        float g = (fqc[i][j][r] + bqb) * (fkc[i][j][r] + bkb);
        sG[row * 72 + j * 16 + l4] = (bf16)g;
      }
  }
  __syncthreads();

  // GEMM2: M = G @ Wfg  (N=128)
  bf16x8 ag[2][2];
#pragma unroll
  for (int i = 0; i < 2; ++i)
#pragma unroll
    for (int kk = 0; kk < 2; ++kk)
      ag[i][kk] = *(const bf16x8*)&sG[(rbase + i * 16 + l4) * 72 + kk * 32 + q8 * 8];
  f32x4 mc[2][8] = {};
#pragma unroll
  for (int jj = 0; jj < 8; ++jj) {
    bf16x8 bg0 = *(const bf16x8*)&sWg[(jj * 16 + l4) * 72 + q8 * 8];
    bf16x8 bg1 = *(const bf16x8*)&sWg[(jj * 16 + l4) * 72 + 32 + q8 * 8];
#pragma unroll
    for (int i = 0; i < 2; ++i) {
      mc[i][jj] = MFMA16(ag[i][0], bg0, mc[i][jj]);
      mc[i][jj] = MFMA16(ag[i][1], bg1, mc[i][jj]);
    }
  }

  // sigmoid + in-place apply (each (row,col) owned by exactly one lane)
  const float SC = 0.18033688011112042f;  // log2(e)/8 folded into Q
#pragma unroll
  for (int jj = 0; jj < 8; ++jj) {
    float bgb = sb[128 + jj * 16 + l4];
    bf16* base = (jj < 4) ? qw : kw;
    float scl = (jj < 4) ? SC : 1.0f;
    int col = (jj & 3) * 16 + l4;
#pragma unroll
    for (int i = 0; i < 2; ++i)
#pragma unroll
      for (int r = 0; r < 4; ++r) {
        int row = T0 + rbase + i * 16 + q8 * 4 + r;
        float m = mc[i][jj][r] + bgb;
        float sig = 1.0f / (1.0f + __expf(-m));
        size_t off = (size_t)row * 64 + col;
        base[off] = (bf16)((float)base[off] * sig * scl);
      }
  }
}

// ------------------------------------------------------------- attention
// block: 256 thr (4 waves), 128 q-rows of one (b,h); wave = 32 rows (2 m-frags).
// K/V streamed in 128-key tiles; online softmax in exp2 domain (scale in Q).
// LDS padded (+8) to break 128B-stride bank aliasing on b128 frag reads.
__global__ __launch_bounds__(256, 2) void k_attn(const bf16* __restrict__ qw,
                                                 const bf16* __restrict__ kw,
                                                 const bf16* __restrict__ vt,
                                                 float* __restrict__ out) {
  __shared__ bf16 Kt[128 * 72];       // [key][dk] padded
  __shared__ bf16 Vt[64 * 136];       // [dk][key] padded (V^T)
  __shared__ bf16 Pb[4][32 * 40];     // per-wave P chunk [32 rows][32 keys] padded
  const int tid = threadIdx.x, w = tid >> 6, l = tid & 63;
  const int l4 = l & 15, q8 = l >> 4;
  const int bx = blockIdx.x, qc = bx & 3, bh = bx >> 2;
  const int b_ = bh >> 4, h = bh & 15;
  bf16* Pw = &Pb[w][0];

  bf16x8 qf[2][2];
#pragma unroll
  for (int i = 0; i < 2; ++i)
#pragma unroll
    for (int kk = 0; kk < 2; ++kk) {
      int s = qc * 128 + w * 32 + i * 16 + l4;
      qf[i][kk] = *(const bf16x8*)
          &qw[(((size_t)b_ * 512 + s) * 16 + h) * 64 + kk * 32 + q8 * 8];
    }

  f32x4 o[2][4] = {};
  float mrun[2][4], lrun[2][4];
#pragma unroll
  for (int i = 0; i < 2; ++i)
#pragma unroll
    for (int r = 0; r < 4; ++r) { mrun[i][r] = -3.0e38f; lrun[i][r] = 0.0f; }

  for (int t = 0; t < 4; ++t) {
    __syncthreads();
#pragma unroll
    for (int i = 0; i < 4; ++i) {
      int chunk = i * 256 + tid;
      {  // K tile: straight copy, [key][dk]
        int key = chunk >> 3, c8 = chunk & 7;
        bf16x8 v = *(const bf16x8*)
            &kw[(((size_t)b_ * 512 + t * 128 + key) * 16 + h) * 64 + c8 * 8];
        *(bf16x8*)&Kt[key * 72 + c8 * 8] = v;
      }
      {  // V^T tile: straight copy from global V^T, [dk][key]
        int d = chunk >> 4, c16 = chunk & 15;
        bf16x8 v = *(const bf16x8*)
            &vt[((size_t)bh * 64 + d) * 512 + t * 128 + c16 * 8];
        *(bf16x8*)&Vt[d * 136 + c16 * 8] = v;
      }
    }
    __syncthreads();

    // scores: D[q (2x16)][key (8x16)]
    f32x4 sc[2][8];
    const f32x4 fz = {};
#pragma unroll
    for (int c = 0; c < 8; ++c) {
      bf16x8 kb0 = *(const bf16x8*)&Kt[(c * 16 + l4) * 72 + q8 * 8];
      sc[0][c] = MFMA16(qf[0][0], kb0, fz);
      sc[1][c] = MFMA16(qf[1][0], kb0, fz);
      bf16x8 kb1 = *(const bf16x8*)&Kt[(c * 16 + l4) * 72 + 32 + q8 * 8];
      sc[0][c] = MFMA16(qf[0][1], kb1, sc[0][c]);
      sc[1][c] = MFMA16(qf[1][1], kb1, sc[1][c]);
    }

    // online softmax (exp2 domain); row stats shared by 16-lane groups
#pragma unroll
    for (int i = 0; i < 2; ++i) {
      float al[4];
#pragma unroll
      for (int r = 0; r < 4; ++r) {
        float mx = sc[i][0][r];
#pragma unroll
        for (int c = 1; c < 8; ++c) mx = fmaxf(mx, sc[i][c][r]);
        mx = fmaxf(mx, __shfl_xor(mx, 1));
        mx = fmaxf(mx, __shfl_xor(mx, 2));
        mx = fmaxf(mx, __shfl_xor(mx, 4));
        mx = fmaxf(mx, __shfl_xor(mx, 8));
        float mn = fmaxf(mrun[i][r], mx);
        al[r] = exp2f(mrun[i][r] - mn);
        mrun[i][r] = mn;
        float sm = 0.0f;
#pragma unroll
        for (int c = 0; c < 8; ++c) {
          float p = exp2f(sc[i][c][r] - mn);
          sc[i][c][r] = p;
          sm += p;
        }
        sm += __shfl_xor(sm, 1); sm += __shfl_xor(sm, 2);
        sm += __shfl_xor(sm, 4); sm += __shfl_xor(sm, 8);
        lrun[i][r] = lrun[i][r] * al[r] + sm;
      }
#pragma unroll
      for (int f = 0; f < 4; ++f)
#pragma unroll
        for (int r = 0; r < 4; ++r) o[i][f][r] *= al[r];
    }

    // PV: C/D-layout P -> LDS (32-key chunks) -> A-layout frags -> MFMA
#pragma unroll
    for (int kk2 = 0; kk2 < 4; ++kk2) {
#pragma unroll
      for (int i = 0; i < 2; ++i)
#pragma unroll
        for (int cc = 0; cc < 2; ++cc) {
          int c = kk2 * 2 + cc;
#pragma unroll
          for (int r = 0; r < 4; ++r)
            Pw[(i * 16 + q8 * 4 + r) * 40 + cc * 16 + l4] = (bf16)sc[i][c][r];
        }
      bf16x8 pa0 = *(const bf16x8*)&Pw[(l4) * 40 + q8 * 8];
      bf16x8 pa1 = *(const bf16x8*)&Pw[(16 + l4) * 40 + q8 * 8];
#pragma unroll
      for (int f = 0; f < 4; ++f) {
        bf16x8 vb = *(const bf16x8*)&Vt[(f * 16 + l4) * 136 + kk2 * 32 + q8 * 8];
        o[0][f] = MFMA16(pa0, vb, o[0][f]);
        o[1][f] = MFMA16(pa1, vb, o[1][f]);
      }
    }
  }

  // epilogue: normalize, write [B,S,E] fp32
#pragma unroll
  for (int i = 0; i < 2; ++i)
#pragma unroll
    for (int r = 0; r < 4; ++r) {
      int srow = qc * 128 + w * 32 + i * 16 + q8 * 4 + r;
      float inv = 1.0f / lrun[i][r];
#pragma unroll
      for (int f = 0; f < 4; ++f)
        out[(((size_t)b_ * 512 + srow) * 16 + h) * 64 + f * 16 + l4] =
            o[i][f][r] * inv;
    }
}

// ---------------------------------------------------------------- launcher
extern "C" void kernel_launch(void* const* d_in, const int* in_sizes, int n_in,
                              void* d_out, int out_size, void* d_ws,
                              size_t ws_size, hipStream_t stream) {
  (void)in_sizes; (void)n_in; (void)out_size; (void)ws_size;
  const float* inp = (const float*)d_in[0];
  const float* Wq  = (const float*)d_in[1];
  const float* bq  = (const float*)d_in[2];
  const float* Wk  = (const float*)d_in[3];
  const float* bk  = (const float*)d_in[4];
  const float* Wv  = (const float*)d_in[5];
  const float* bv  = (const float*)d_in[6];
  const float* Wfq = (const float*)d_in[7];
  const float* bfq = (const float*)d_in[8];
  const float* Wfk = (const float*)d_in[9];
  const float* bfk = (const float*)d_in[10];
  const float* Wfg = (const float*)d_in[11];
  const float* bfg = (const float*)d_in[12];
  float* out = (float*)d_out;

  char* ws = (char*)d_ws;
  bf16* Xb = (bf16*)(ws);                                // 16 MB
  bf16* WT = (bf16*)(ws + 16777216);                     // 6 MB (3x W^T)
  bf16* qw = (bf16*)(ws + 16777216 + 6291456);           // 16 MB [B,S,H,DK]
  bf16* kw = qw + 8388608;                               // 16 MB
  bf16* vt = kw + 8388608;                               // 16 MB [B,H,DK,S]

  k_conv_inp<<<8192, 256, 0, stream>>>(inp, Xb);
  k_wt<<<dim3(32, 32, 3), 256, 0, stream>>>(Wq, Wk, Wv, WT);
  k_proj<<<dim3(64, 24), 256, 0, stream>>>(Xb, WT, bq, bk, bv, qw, kw, vt);
  k_gate<<<1024, 256, 0, stream>>>(qw, kw, Wfq, bfq, Wfk, bfk, Wfg, bfg);
  k_attn<<<1024, 256, 0, stream>>>(qw, kw, vt, out);
}